// Round 8
// baseline (399.199 us; speedup 1.0000x reference)
//
#include <hip/hip_runtime.h>
#include <hip/hip_fp16.h>

typedef _Float16 half8 __attribute__((ext_vector_type(8)));
typedef float f32x4 __attribute__((ext_vector_type(4)));

#define HID 128
#define NDIM 16
#define NCONV 8

static __device__ __forceinline__ half8 load_h8(const _Float16* p) {
    return *(const half8*)p;
}

// ---------------- weight prep: f16 transposed weights ----------------
// WABT[l] : [256][128] f16. rows j<128:  W1A_T[j][k] = W1[l][k][j] - W1[l][128+k][j]
//                           rows 128+j:  W1B_T[j][k] = W1[l][128+k][j]
// W2T[l]  : [128][128] f16. W2T[j][k] = W2[l][k][j]
// tail range: encT[j][k] = eW[k][j]
__global__ void prep_weights(const float* __restrict__ W1, const float* __restrict__ W2,
                             const float* __restrict__ eW,
                             _Float16* __restrict__ WABT, _Float16* __restrict__ W2T,
                             _Float16* __restrict__ encT) {
    int idx = blockIdx.x * blockDim.x + threadIdx.x;
    int total = NCONV * HID * HID;
    if (idx < total) {
        int l = idx / (HID * HID);
        int r = idx % (HID * HID);
        int j = r / HID;
        int k = r % HID;
        const float* w1 = W1 + (size_t)l * 2 * HID * HID;
        float top = w1[k * HID + j];
        float bot = w1[(HID + k) * HID + j];
        _Float16* wab = WABT + (size_t)l * 2 * HID * HID;
        wab[j * HID + k] = (_Float16)(top - bot);
        wab[(HID + j) * HID + k] = (_Float16)bot;
        const float* w2 = W2 + (size_t)l * HID * HID;
        W2T[(size_t)l * HID * HID + j * HID + k] = (_Float16)w2[k * HID + j];
    } else if (idx < total + HID * HID) {
        int r = idx - total;
        int j = r / HID;
        int k = r % HID;
        encT[j * HID + k] = (_Float16)eW[k * HID + j];
    }
}

// ---------------- time embedding ----------------
__global__ void time_emb_kernel(const float* __restrict__ t, const float* __restrict__ tpW,
                                const float* __restrict__ tpb, float* __restrict__ temb) {
    __shared__ float sc[64];
    int i = threadIdx.x;
    float tv = t[0];
    if (i < 32) {
        float f = expf(-4.0f + 8.0f * (float)i / 31.0f);
        sc[i] = sinf(tv * f);
        sc[32 + i] = cosf(tv * f);
    }
    __syncthreads();
    if (i < 16) {
        float acc = tpb[i];
        for (int k = 0; k < 64; k++) acc += sc[k] * tpW[k * NDIM + i];
        temb[i] = acc;
    }
}

// ---------------- node embedding: h = (x + temb) @ neW + neb -> f16 ----------------
__global__ void node_emb_kernel(const float* __restrict__ x, const float* __restrict__ temb,
                                const float* __restrict__ W, const float* __restrict__ b,
                                _Float16* __restrict__ h16, int n) {
    __shared__ float sx[NDIM];
    int node = blockIdx.x;
    if (node >= n) return;
    int j = threadIdx.x;
    if (j < NDIM) sx[j] = x[(size_t)node * NDIM + j] + temb[j];
    __syncthreads();
    float acc = b[j];
    #pragma unroll
    for (int d = 0; d < NDIM; d++) acc += sx[d] * W[d * HID + j];
    h16[(size_t)node * HID + j] = (_Float16)acc;
}

// ---------------- CSR build ----------------
__global__ void count_deg(const int* __restrict__ ei, int* __restrict__ deg, int E) {
    int e = blockIdx.x * blockDim.x + threadIdx.x;
    if (e < E) atomicAdd(&deg[ei[E + e]], 1);   // dst row
}

__global__ void scan_csr(const int* __restrict__ deg, int* __restrict__ rowptr,
                         int* __restrict__ cursor, int n) {
    __shared__ int part[1024];
    int t = threadIdx.x;
    int chunk = (n + 1023) / 1024;
    int base = t * chunk;
    int s = 0;
    for (int i = 0; i < chunk; i++) {
        int id = base + i;
        if (id < n) s += deg[id];
    }
    part[t] = s;
    __syncthreads();
    for (int off = 1; off < 1024; off <<= 1) {
        int v = 0;
        if (t >= off) v = part[t - off];
        __syncthreads();
        part[t] += v;
        __syncthreads();
    }
    int pre = (t == 0) ? 0 : part[t - 1];
    for (int i = 0; i < chunk; i++) {
        int id = base + i;
        if (id < n) {
            rowptr[id] = pre;
            cursor[id] = pre;
            pre += deg[id];
        }
    }
    if (t == 1023) rowptr[n] = part[1023];
}

__global__ void fill_csr(const int* __restrict__ ei, int* __restrict__ cursor,
                         int* __restrict__ elist, int E) {
    int e = blockIdx.x * blockDim.x + threadIdx.x;
    if (e < E) {
        int d = ei[E + e];
        int pos = atomicAdd(&cursor[d], 1);
        elist[pos] = ei[e];   // src
    }
}

// ---------------- generic node GEMM: Y[n][OUT] = A[n][128] @ WT^T + bias ----------------
template<int OUT>
__global__ __launch_bounds__(256) void gemm_h(const _Float16* __restrict__ A,
                                              const _Float16* __restrict__ WT,
                                              const float* __restrict__ bias,
                                              _Float16* __restrict__ Y, int n) {
    constexpr int JW = OUT / 32;    // j-pairs per m-tile
    int gw = (blockIdx.x * blockDim.x + threadIdx.x) >> 6;
    int lane = threadIdx.x & 63;
    int nmt = (n + 15) >> 4;
    if (gw >= nmt * JW) return;
    int mt = gw / JW;
    int jp = gw % JW;
    int c = lane & 15;
    int kq = lane >> 4;

    int arow = mt * 16 + c;
    half8 a[4];
    #pragma unroll
    for (int kb = 0; kb < 4; kb++) {
        if (arow < n) a[kb] = load_h8(A + (size_t)arow * HID + kb * 32 + kq * 8);
        else          a[kb] = (half8)(_Float16)0;
    }

    f32x4 acc[2];
    #pragma unroll
    for (int p = 0; p < 2; p++) {
        acc[p][0] = 0.f; acc[p][1] = 0.f; acc[p][2] = 0.f; acc[p][3] = 0.f;
        int wrow = (jp * 2 + p) * 16 + c;
        #pragma unroll
        for (int kb = 0; kb < 4; kb++) {
            half8 b = load_h8(WT + (size_t)wrow * HID + kb * 32 + kq * 8);
            acc[p] = __builtin_amdgcn_mfma_f32_16x16x32_f16(a[kb], b, acc[p], 0, 0, 0);
        }
    }

    #pragma unroll
    for (int p = 0; p < 2; p++) {
        int col = (jp * 2 + p) * 16 + c;
        float bv = (col < HID) ? bias[col] : 0.f;
        #pragma unroll
        for (int r = 0; r < 4; r++) {
            int row = mt * 16 + kq * 4 + r;
            if (row < n) Y[(size_t)row * OUT + col] = (_Float16)(acc[p][r] + bv);
        }
    }
}

// ---------------- EdgeConv: out[v][j] = max_e relu(A[v]+B[src_e]) @ W2 + b2 ----------------
// 16-edge tiles (16x16x32 MFMA) with a TILE-LEVEL DATA double-buffer in registers:
// while tile T computes, tile T+1's B-fragments (16 VGPRs) are in flight and the
// src indices for tile T+2 are being loaded — the elist->gather chain never sits on
// the critical path. The tile stream crosses node boundaries via a 3-node CSR window
// (v, vn, vn2); next node's af row is prefetched before the reduce/store.
// W2 in LDS, fragment-major (0 bank conflicts, r3-verified). No min-waves bound
// (r2/r3 lesson: forced reg budget -> 200 MB spill traffic).
__global__ __launch_bounds__(512) void edge_conv(const _Float16* __restrict__ AB,
                                                 const _Float16* __restrict__ W2T_l,
                                                 const float* __restrict__ b2_l,
                                                 const int* __restrict__ rowptr,
                                                 const int* __restrict__ elist,
                                                 _Float16* __restrict__ hout, int n) {
    __shared__ _Float16 w2s[2048 * 8];   // 2048 frags x 16B = 32 KB
    __shared__ float b2s[HID];
    int tid = threadIdx.x;
    #pragma unroll
    for (int i = 0; i < 4; i++) {
        int fid = i * 512 + tid;
        int fc = fid & 15;
        int fkq = (fid >> 4) & 3;
        int grp = fid >> 6;          // kb*8+cb
        int fkb = grp >> 3;
        int fcb = grp & 7;
        *(half8*)(w2s + (size_t)fid * 8) =
            load_h8(W2T_l + (size_t)(fcb * 16 + fc) * HID + fkb * 32 + fkq * 8);
    }
    if (tid < HID) b2s[tid] = b2_l[tid];
    __syncthreads();

    int lane = tid & 63;
    int c = lane & 15;
    int kq = lane >> 4;
    int gw = (blockIdx.x * blockDim.x + tid) >> 6;
    int nw = (gridDim.x * blockDim.x) >> 6;
    if (gw >= n) return;

    // ---- 3-node window state ----
    int v = gw;
    int rbeg0 = rowptr[v];
    int deg0 = rowptr[v + 1] - rbeg0;
    int nt0 = (deg0 + 16) >> 4;          // ceil((deg0+1)/16)
    int vn = v + nw;
    int rbeg1 = 0, deg1 = 0;
    if (vn < n) { rbeg1 = rowptr[vn]; deg1 = rowptr[vn + 1] - rbeg1; }
    int vn2 = vn + nw;
    int rbeg2 = 0, deg2 = 0;
    if (vn2 < n) { rbeg2 = rowptr[vn2]; deg2 = rowptr[vn2 + 1] - rbeg2; }

    // src indices for global tile g of the stream (g counts tiles of v, then vn, then vn2)
    auto tsrc = [&](int g) -> int {
        int nt1 = (deg1 + 16) >> 4;
        int rb, dg, sf, gl;
        if (g < nt0)            { rb = rbeg0; dg = deg0; sf = v;   gl = g; }
        else if (g < nt0 + nt1) { rb = rbeg1; dg = deg1; sf = vn;  gl = g - nt0; }
        else                    { rb = rbeg2; dg = deg2; sf = vn2; gl = g - nt0 - nt1; }
        int idx = gl * 16 + c;
        int s = (idx < dg) ? elist[rb + idx] : sf;   // pad = self-loop (max-invariant)
        return (s < n) ? s : 0;                      // clamp phantom tiles (never consumed)
    };

    // af fragments of node v
    half8 af[4];
    #pragma unroll
    for (int kb = 0; kb < 4; kb++)
        af[kb] = load_h8(AB + (size_t)v * 256 + kb * 32 + kq * 8);

    // prime the pipeline: bsC = B-data of tile 0; sN = srcs of tile 1
    int s0 = tsrc(0);
    half8 bsC[4];
    {
        const _Float16* bp = AB + (size_t)s0 * 256 + 128 + kq * 8;
        #pragma unroll
        for (int kb = 0; kb < 4; kb++) bsC[kb] = load_h8(bp + kb * 32);
    }
    int sN = tsrc(1);

    while (true) {
        float macc[8];
        #pragma unroll
        for (int cb = 0; cb < 8; cb++) macc[cb] = -3.0e38f;

        for (int tI = 0; tI < nt0; tI++) {
            // prefetch tile tI+1's B-data (regs) and tile tI+2's src indices
            half8 bsN[4];
            {
                const _Float16* bp = AB + (size_t)sN * 256 + 128 + kq * 8;
                #pragma unroll
                for (int kb = 0; kb < 4; kb++) bsN[kb] = load_h8(bp + kb * 32);
            }
            int sNN = tsrc(tI + 2);

            // compute tile tI from bsC (in regs since previous tile)
            f32x4 d[8];
            #pragma unroll
            for (int cb = 0; cb < 8; cb++) { d[cb][0] = 0.f; d[cb][1] = 0.f; d[cb][2] = 0.f; d[cb][3] = 0.f; }
            #pragma unroll
            for (int kb = 0; kb < 4; kb++) {
                half8 s = af[kb] + bsC[kb];
                #pragma unroll
                for (int e = 0; e < 8; e++) s[e] = (s[e] > (_Float16)0) ? s[e] : (_Float16)0;
                #pragma unroll
                for (int cb = 0; cb < 8; cb++) {
                    half8 w = *(const half8*)(w2s + ((size_t)((kb * 8 + cb) * 64 + lane)) * 8);
                    d[cb] = __builtin_amdgcn_mfma_f32_16x16x32_f16(s, w, d[cb], 0, 0, 0);
                }
            }
            #pragma unroll
            for (int cb = 0; cb < 8; cb++) {
                float m0 = fmaxf(fmaxf(d[cb][0], d[cb][1]), fmaxf(d[cb][2], d[cb][3]));
                macc[cb] = fmaxf(macc[cb], m0);
            }
            // rotate tile pipeline
            #pragma unroll
            for (int kb = 0; kb < 4; kb++) bsC[kb] = bsN[kb];
            sN = sNN;
        }

        // prefetch next node's af before the reduce (hides its latency behind reduce+store)
        half8 afn[4];
        if (vn < n) {
            #pragma unroll
            for (int kb = 0; kb < 4; kb++)
                afn[kb] = load_h8(AB + (size_t)vn * 256 + kb * 32 + kq * 8);
        }

        #pragma unroll
        for (int cb = 0; cb < 8; cb++) {
            float m = macc[cb];
            m = fmaxf(m, __shfl_xor(m, 16));
            m = fmaxf(m, __shfl_xor(m, 32));
            m += b2s[cb * 16 + c];
            if (lane < 16) hout[(size_t)v * HID + cb * 16 + c] = (_Float16)m;
        }

        // ---- advance node window ----
        v = vn;
        if (v >= n) break;
        #pragma unroll
        for (int kb = 0; kb < 4; kb++) af[kb] = afn[kb];
        rbeg0 = rbeg1; deg0 = deg1; nt0 = (deg0 + 16) >> 4;
        vn = v + nw;
        rbeg1 = rbeg2; deg1 = deg2;
        vn2 = vn + nw;
        if (vn2 < n) { rbeg2 = rowptr[vn2]; deg2 = rowptr[vn2 + 1] - rbeg2; }
        else { rbeg2 = 0; deg2 = 0; }
        // bsC / sN already hold the new node's tile0 data / tile1 srcs
    }
}

// ---------------- decoder FC: out = h @ dW + db  (fp32 out [N][16]) ----------------
__global__ void fc_dec(const _Float16* __restrict__ h16, const float* __restrict__ W,
                       const float* __restrict__ b, float* __restrict__ out, int n) {
    __shared__ float row[HID];
    __shared__ float part[64];
    int node = blockIdx.x;
    if (node >= n) return;
    int t = threadIdx.x;
    row[t] = (float)h16[(size_t)node * HID + t];
    row[64 + t] = (float)h16[(size_t)node * HID + 64 + t];
    __syncthreads();
    int j = t & 15;
    int ks = t >> 4;   // 0..3, each covers 32 k
    float p = 0.f;
    for (int k = ks * 32; k < ks * 32 + 32; k++) p += row[k] * W[k * NDIM + j];
    part[t] = p;
    __syncthreads();
    if (t < 16) {
        float o = b[j] + part[j] + part[16 + j] + part[32 + j] + part[48 + j];
        out[(size_t)node * NDIM + j] = o;
    }
}

// ---------------- host ----------------
extern "C" void kernel_launch(void* const* d_in, const int* in_sizes, int n_in,
                              void* d_out, int out_size, void* d_ws, size_t ws_size,
                              hipStream_t stream) {
    const float* x   = (const float*)d_in[0];
    const int*   ei  = (const int*)d_in[1];
    const float* t   = (const float*)d_in[2];
    const float* neW = (const float*)d_in[3];
    const float* neb = (const float*)d_in[4];
    const float* cW1 = (const float*)d_in[5];
    const float* cb1 = (const float*)d_in[6];
    const float* cW2 = (const float*)d_in[7];
    const float* cb2 = (const float*)d_in[8];
    const float* eW  = (const float*)d_in[9];
    const float* eb  = (const float*)d_in[10];
    const float* dW  = (const float*)d_in[11];
    const float* db  = (const float*)d_in[12];
    const float* tpW = (const float*)d_in[13];
    const float* tpb = (const float*)d_in[14];

    int N = in_sizes[0] / NDIM;
    int E = in_sizes[1] / 2;

    char* w = (char*)d_ws;
    auto alloc = [&](size_t bytes) {
        void* p = (void*)w;
        w += (bytes + 255) & ~(size_t)255;
        return p;
    };
    float*     temb   = (float*)alloc(64 * 4);
    _Float16*  hA     = (_Float16*)alloc((size_t)N * HID * 2);
    _Float16*  hB     = (_Float16*)alloc((size_t)N * HID * 2);
    _Float16*  AB     = (_Float16*)alloc((size_t)N * 2 * HID * 2);
    _Float16*  WABT   = (_Float16*)alloc((size_t)NCONV * 2 * HID * HID * 2);
    _Float16*  W2T    = (_Float16*)alloc((size_t)NCONV * HID * HID * 2);
    _Float16*  encT   = (_Float16*)alloc((size_t)HID * HID * 2);
    int*       deg    = (int*)alloc((size_t)N * 4);
    int*       rowptr = (int*)alloc((size_t)(N + 1) * 4);
    int*       cursor = (int*)alloc((size_t)N * 4);
    int*       elist  = (int*)alloc((size_t)E * 4);

    // weights + time embedding + node embedding
    int prep_total = NCONV * HID * HID + HID * HID;
    prep_weights<<<(prep_total + 255) / 256, 256, 0, stream>>>(cW1, cW2, eW, WABT, W2T, encT);
    time_emb_kernel<<<1, 64, 0, stream>>>(t, tpW, tpb, temb);
    node_emb_kernel<<<N, HID, 0, stream>>>(x, temb, neW, neb, hA, N);

    // CSR by dst
    hipMemsetAsync(deg, 0, (size_t)N * 4, stream);
    count_deg<<<(E + 255) / 256, 256, 0, stream>>>(ei, deg, E);
    scan_csr<<<1, 1024, 0, stream>>>(deg, rowptr, cursor, N);
    fill_csr<<<(E + 255) / 256, 256, 0, stream>>>(ei, cursor, elist, E);

    int nmt = (N + 15) / 16;
    int ab_blocks = (nmt * 8 + 3) / 4;      // OUT=256 -> JW=8
    int fc_blocks = (nmt * 4 + 3) / 4;      // OUT=128 -> JW=4
    int ec_blocks = 512;                    // 512 thr/block: 2 blocks/CU, 16 waves/CU

    _Float16* cur = hA;
    for (int l = 0; l < NCONV; l++) {
        if (l == 4) {
            gemm_h<128><<<fc_blocks, 256, 0, stream>>>(cur, encT, eb, hB, N);
            cur = hB;
        }
        gemm_h<256><<<ab_blocks, 256, 0, stream>>>(cur, WABT + (size_t)l * 2 * HID * HID,
                                                   cb1 + (size_t)l * HID, AB, N);
        edge_conv<<<ec_blocks, 512, 0, stream>>>(AB, W2T + (size_t)l * HID * HID,
                                                 cb2 + (size_t)l * HID, rowptr, elist, cur, N);
    }

    fc_dec<<<N, HID, 0, stream>>>(cur, dW, db, (float*)d_out, N);
}

// Round 9
// 336.395 us; speedup vs baseline: 1.1867x; 1.1867x over previous
//
#include <hip/hip_runtime.h>
#include <hip/hip_fp16.h>

typedef _Float16 half8 __attribute__((ext_vector_type(8)));
typedef float f32x4 __attribute__((ext_vector_type(4)));
typedef float f32x16 __attribute__((ext_vector_type(16)));

#define HID 128
#define NDIM 16
#define NCONV 8

static __device__ __forceinline__ half8 load_h8(const _Float16* p) {
    return *(const half8*)p;
}

// ---------------- weight prep: f16 transposed weights ----------------
// WABT[l] : [256][128] f16. rows j<128:  W1A_T[j][k] = W1[l][k][j] - W1[l][128+k][j]
//                           rows 128+j:  W1B_T[j][k] = W1[l][128+k][j]
// W2T[l]  : [128][128] f16. W2T[j][k] = W2[l][k][j]
// tail range: encT[j][k] = eW[k][j]
__global__ void prep_weights(const float* __restrict__ W1, const float* __restrict__ W2,
                             const float* __restrict__ eW,
                             _Float16* __restrict__ WABT, _Float16* __restrict__ W2T,
                             _Float16* __restrict__ encT) {
    int idx = blockIdx.x * blockDim.x + threadIdx.x;
    int total = NCONV * HID * HID;
    if (idx < total) {
        int l = idx / (HID * HID);
        int r = idx % (HID * HID);
        int j = r / HID;
        int k = r % HID;
        const float* w1 = W1 + (size_t)l * 2 * HID * HID;
        float top = w1[k * HID + j];
        float bot = w1[(HID + k) * HID + j];
        _Float16* wab = WABT + (size_t)l * 2 * HID * HID;
        wab[j * HID + k] = (_Float16)(top - bot);
        wab[(HID + j) * HID + k] = (_Float16)bot;
        const float* w2 = W2 + (size_t)l * HID * HID;
        W2T[(size_t)l * HID * HID + j * HID + k] = (_Float16)w2[k * HID + j];
    } else if (idx < total + HID * HID) {
        int r = idx - total;
        int j = r / HID;
        int k = r % HID;
        encT[j * HID + k] = (_Float16)eW[k * HID + j];
    }
}

// ---------------- time embedding ----------------
__global__ void time_emb_kernel(const float* __restrict__ t, const float* __restrict__ tpW,
                                const float* __restrict__ tpb, float* __restrict__ temb) {
    __shared__ float sc[64];
    int i = threadIdx.x;
    float tv = t[0];
    if (i < 32) {
        float f = expf(-4.0f + 8.0f * (float)i / 31.0f);
        sc[i] = sinf(tv * f);
        sc[32 + i] = cosf(tv * f);
    }
    __syncthreads();
    if (i < 16) {
        float acc = tpb[i];
        for (int k = 0; k < 64; k++) acc += sc[k] * tpW[k * NDIM + i];
        temb[i] = acc;
    }
}

// ---------------- node embedding: h = (x + temb) @ neW + neb -> f16 ----------------
__global__ void node_emb_kernel(const float* __restrict__ x, const float* __restrict__ temb,
                                const float* __restrict__ W, const float* __restrict__ b,
                                _Float16* __restrict__ h16, int n) {
    __shared__ float sx[NDIM];
    int node = blockIdx.x;
    if (node >= n) return;
    int j = threadIdx.x;
    if (j < NDIM) sx[j] = x[(size_t)node * NDIM + j] + temb[j];
    __syncthreads();
    float acc = b[j];
    #pragma unroll
    for (int d = 0; d < NDIM; d++) acc += sx[d] * W[d * HID + j];
    h16[(size_t)node * HID + j] = (_Float16)acc;
}

// ---------------- CSR build ----------------
__global__ void count_deg(const int* __restrict__ ei, int* __restrict__ deg, int E) {
    int e = blockIdx.x * blockDim.x + threadIdx.x;
    if (e < E) atomicAdd(&deg[ei[E + e]], 1);   // dst row
}

__global__ void scan_csr(const int* __restrict__ deg, int* __restrict__ rowptr,
                         int* __restrict__ cursor, int n) {
    __shared__ int part[1024];
    int t = threadIdx.x;
    int chunk = (n + 1023) / 1024;
    int base = t * chunk;
    int s = 0;
    for (int i = 0; i < chunk; i++) {
        int id = base + i;
        if (id < n) s += deg[id];
    }
    part[t] = s;
    __syncthreads();
    for (int off = 1; off < 1024; off <<= 1) {
        int v = 0;
        if (t >= off) v = part[t - off];
        __syncthreads();
        part[t] += v;
        __syncthreads();
    }
    int pre = (t == 0) ? 0 : part[t - 1];
    for (int i = 0; i < chunk; i++) {
        int id = base + i;
        if (id < n) {
            rowptr[id] = pre;
            cursor[id] = pre;
            pre += deg[id];
        }
    }
    if (t == 1023) rowptr[n] = part[1023];
}

__global__ void fill_csr(const int* __restrict__ ei, int* __restrict__ cursor,
                         int* __restrict__ elist, int E) {
    int e = blockIdx.x * blockDim.x + threadIdx.x;
    if (e < E) {
        int d = ei[E + e];
        int pos = atomicAdd(&cursor[d], 1);
        elist[pos] = ei[e];   // src
    }
}

// ---------------- AB gemm: Atab[n][128] = h@W1A + b1 ; Btab[n][128] = h@W1B ----------------
// Split tables (was interleaved AB[n][256]): the gathered table (Btab) is 2.5 MB
// -> fully L2-resident per XCD (4 MiB), cutting gather latency L3->L2.
__global__ __launch_bounds__(256) void ab_gemm(const _Float16* __restrict__ A,
                                               const _Float16* __restrict__ WT,
                                               const float* __restrict__ bias,
                                               _Float16* __restrict__ Atab,
                                               _Float16* __restrict__ Btab, int n) {
    int gw = (blockIdx.x * blockDim.x + threadIdx.x) >> 6;
    int lane = threadIdx.x & 63;
    int nmt = (n + 15) >> 4;
    if (gw >= nmt * 8) return;
    int mt = gw >> 3;
    int jp = gw & 7;
    int c = lane & 15;
    int kq = lane >> 4;

    int arow = mt * 16 + c;
    half8 a[4];
    #pragma unroll
    for (int kb = 0; kb < 4; kb++) {
        if (arow < n) a[kb] = load_h8(A + (size_t)arow * HID + kb * 32 + kq * 8);
        else          a[kb] = (half8)(_Float16)0;
    }

    f32x4 acc[2];
    #pragma unroll
    for (int p = 0; p < 2; p++) {
        acc[p][0] = 0.f; acc[p][1] = 0.f; acc[p][2] = 0.f; acc[p][3] = 0.f;
        int wrow = (jp * 2 + p) * 16 + c;
        #pragma unroll
        for (int kb = 0; kb < 4; kb++) {
            half8 b = load_h8(WT + (size_t)wrow * HID + kb * 32 + kq * 8);
            acc[p] = __builtin_amdgcn_mfma_f32_16x16x32_f16(a[kb], b, acc[p], 0, 0, 0);
        }
    }

    #pragma unroll
    for (int p = 0; p < 2; p++) {
        int col = (jp * 2 + p) * 16 + c;
        float bv = (col < HID) ? bias[col] : 0.f;
        _Float16* dst = (col < HID) ? Atab : Btab;
        int dcol = col & (HID - 1);
        #pragma unroll
        for (int r = 0; r < 4; r++) {
            int row = mt * 16 + kq * 4 + r;
            if (row < n) dst[(size_t)row * HID + dcol] = (_Float16)(acc[p][r] + bv);
        }
    }
}

// ---------------- generic node GEMM: Y[n][OUT] = A[n][128] @ WT^T + bias ----------------
template<int OUT>
__global__ __launch_bounds__(256) void gemm_h(const _Float16* __restrict__ A,
                                              const _Float16* __restrict__ WT,
                                              const float* __restrict__ bias,
                                              _Float16* __restrict__ Y, int n) {
    constexpr int JW = OUT / 32;    // j-pairs per m-tile
    int gw = (blockIdx.x * blockDim.x + threadIdx.x) >> 6;
    int lane = threadIdx.x & 63;
    int nmt = (n + 15) >> 4;
    if (gw >= nmt * JW) return;
    int mt = gw / JW;
    int jp = gw % JW;
    int c = lane & 15;
    int kq = lane >> 4;

    int arow = mt * 16 + c;
    half8 a[4];
    #pragma unroll
    for (int kb = 0; kb < 4; kb++) {
        if (arow < n) a[kb] = load_h8(A + (size_t)arow * HID + kb * 32 + kq * 8);
        else          a[kb] = (half8)(_Float16)0;
    }

    f32x4 acc[2];
    #pragma unroll
    for (int p = 0; p < 2; p++) {
        acc[p][0] = 0.f; acc[p][1] = 0.f; acc[p][2] = 0.f; acc[p][3] = 0.f;
        int wrow = (jp * 2 + p) * 16 + c;
        #pragma unroll
        for (int kb = 0; kb < 4; kb++) {
            half8 b = load_h8(WT + (size_t)wrow * HID + kb * 32 + kq * 8);
            acc[p] = __builtin_amdgcn_mfma_f32_16x16x32_f16(a[kb], b, acc[p], 0, 0, 0);
        }
    }

    #pragma unroll
    for (int p = 0; p < 2; p++) {
        int col = (jp * 2 + p) * 16 + c;
        float bv = (col < HID) ? bias[col] : 0.f;
        #pragma unroll
        for (int r = 0; r < 4; r++) {
            int row = mt * 16 + kq * 4 + r;
            if (row < n) Y[(size_t)row * OUT + col] = (_Float16)(acc[p][r] + bv);
        }
    }
}

// ---------------- EdgeConv: out[v][j] = max_e relu(A[v]+B[src_e]) @ W2 + b2 ----------------
// r6 structure (best + simplest): 32x32x16 MFMA, 32-edge tiles (~1 tile/node at avg
// deg+1=18). Gathers hit the L2-resident 2.5 MB Btab. W2 in LDS fragment-major
// (0 bank conflicts, r3-verified). Scalar running max collapses the f32x16 acc
// right after each K-loop (max over rows is layout-permutation-immune).
// Cross-node prefetch: rowptr/deg + first-tile src (scalars only — r8 showed
// data-prefetch VALU overhead regresses).
// NOTE: no min-waves launch bound (r2/r3 lesson: forced budget -> 200 MB spills).
__global__ __launch_bounds__(512) void edge_conv(const _Float16* __restrict__ Atab,
                                                 const _Float16* __restrict__ Btab,
                                                 const _Float16* __restrict__ W2T_l,
                                                 const float* __restrict__ b2_l,
                                                 const int* __restrict__ rowptr,
                                                 const int* __restrict__ elist,
                                                 _Float16* __restrict__ hout, int n) {
    __shared__ _Float16 w2s[2048 * 8];   // 32 frags (kb*4+cb) x 64 lanes x 16B = 32 KB
    __shared__ float b2s[HID];
    int tid = threadIdx.x;
    #pragma unroll
    for (int i = 0; i < 4; i++) {
        int fid = i * 512 + tid;     // 0..2047
        int ln = fid & 63;
        int grp = fid >> 6;          // kb*4+cb
        int kb = grp >> 2;
        int cb = grp & 3;
        *(half8*)(w2s + (size_t)fid * 8) =
            load_h8(W2T_l + (size_t)(cb * 32 + (ln & 31)) * HID + kb * 16 + (ln >> 5) * 8);
    }
    if (tid < HID) b2s[tid] = b2_l[tid];
    __syncthreads();

    int lane = tid & 63;
    int er = lane & 31;     // edge-row within tile / output col within cb block
    int hi = lane >> 5;     // k-half
    int gw = (blockIdx.x * blockDim.x + tid) >> 6;
    int nw = (gridDim.x * blockDim.x) >> 6;
    if (gw >= n) return;

    // ---- pipeline prologue ----
    int v = gw;
    int rbeg0 = rowptr[v];
    int deg0 = rowptr[v + 1] - rbeg0;
    int src0 = (er < deg0) ? elist[rbeg0 + er] : v;
    int v1 = v + nw;
    int rbeg1 = 0, deg1 = 0;
    if (v1 < n) { rbeg1 = rowptr[v1]; deg1 = rowptr[v1 + 1] - rbeg1; }

    while (true) {
        int vn = v + nw;
        int vn2 = vn + nw;
        int rbeg2 = 0, deg2 = 0;
        if (vn2 < n) { rbeg2 = rowptr[vn2]; deg2 = rowptr[vn2 + 1] - rbeg2; }
        int src1 = (er < deg1) ? elist[rbeg1 + er] : vn;

        // A-half slices of node v: k = kb*16 + hi*8 + j
        const _Float16* ap = Atab + (size_t)v * HID + hi * 8;
        half8 af[8];
        #pragma unroll
        for (int kb = 0; kb < 8; kb++) af[kb] = load_h8(ap + kb * 16);

        int ntile = (deg0 + 32) >> 5;        // ceil((deg0+1)/32), pad = self-loop
        float macc[4];
        #pragma unroll
        for (int cb = 0; cb < 4; cb++) macc[cb] = -3.0e38f;

        int src = src0;
        for (int tI = 0; tI < ntile; tI++) {
            // gather B slices of this lane's edge (L2-resident Btab)
            const _Float16* bp = Btab + (size_t)src * HID + hi * 8;
            half8 s[8];
            #pragma unroll
            for (int kb = 0; kb < 8; kb++) s[kb] = load_h8(bp + kb * 16);

            // prefetch next tile's src (overlaps with compute)
            int en = (tI + 1) * 32 + er;
            int srcn = (tI + 1 < ntile && en < deg0) ? elist[rbeg0 + en] : v;

            // s = relu(af + s)
            #pragma unroll
            for (int kb = 0; kb < 8; kb++) {
                half8 t = af[kb] + s[kb];
                #pragma unroll
                for (int e2 = 0; e2 < 8; e2++) t[e2] = (t[e2] > (_Float16)0) ? t[e2] : (_Float16)0;
                s[kb] = t;
            }

            #pragma unroll
            for (int cb = 0; cb < 4; cb++) {
                f32x16 d;
                #pragma unroll
                for (int e2 = 0; e2 < 16; e2++) d[e2] = 0.f;
                #pragma unroll
                for (int kb = 0; kb < 8; kb++) {
                    half8 w = *(const half8*)(w2s + ((size_t)((kb * 4 + cb) * 64 + lane)) * 8);
                    d = __builtin_amdgcn_mfma_f32_32x32x16_f16(s[kb], w, d, 0, 0, 0);
                }
                // tree-max the 16 row values (row mapping irrelevant for max)
                float m0 = fmaxf(fmaxf(d[0], d[1]), fmaxf(d[2], d[3]));
                float m1 = fmaxf(fmaxf(d[4], d[5]), fmaxf(d[6], d[7]));
                float m2 = fmaxf(fmaxf(d[8], d[9]), fmaxf(d[10], d[11]));
                float m3 = fmaxf(fmaxf(d[12], d[13]), fmaxf(d[14], d[15]));
                macc[cb] = fmaxf(macc[cb], fmaxf(fmaxf(m0, m1), fmaxf(m2, m3)));
            }
            src = srcn;
        }

        // merge k-half partners (other 16 rows) and write
        #pragma unroll
        for (int cb = 0; cb < 4; cb++) {
            float m = fmaxf(macc[cb], __shfl_xor(macc[cb], 32));
            m += b2s[cb * 32 + er];
            if (lane < 32) hout[(size_t)v * HID + cb * 32 + er] = (_Float16)m;
        }

        // ---- rotate pipeline ----
        v = vn;
        if (v >= n) break;
        src0 = src1;
        rbeg0 = rbeg1; deg0 = deg1;
        rbeg1 = rbeg2; deg1 = deg2;
    }
}

// ---------------- decoder FC: out = h @ dW + db  (fp32 out [N][16]) ----------------
__global__ void fc_dec(const _Float16* __restrict__ h16, const float* __restrict__ W,
                       const float* __restrict__ b, float* __restrict__ out, int n) {
    __shared__ float row[HID];
    __shared__ float part[64];
    int node = blockIdx.x;
    if (node >= n) return;
    int t = threadIdx.x;
    row[t] = (float)h16[(size_t)node * HID + t];
    row[64 + t] = (float)h16[(size_t)node * HID + 64 + t];
    __syncthreads();
    int j = t & 15;
    int ks = t >> 4;   // 0..3, each covers 32 k
    float p = 0.f;
    for (int k = ks * 32; k < ks * 32 + 32; k++) p += row[k] * W[k * NDIM + j];
    part[t] = p;
    __syncthreads();
    if (t < 16) {
        float o = b[j] + part[j] + part[16 + j] + part[32 + j] + part[48 + j];
        out[(size_t)node * NDIM + j] = o;
    }
}

// ---------------- host ----------------
extern "C" void kernel_launch(void* const* d_in, const int* in_sizes, int n_in,
                              void* d_out, int out_size, void* d_ws, size_t ws_size,
                              hipStream_t stream) {
    const float* x   = (const float*)d_in[0];
    const int*   ei  = (const int*)d_in[1];
    const float* t   = (const float*)d_in[2];
    const float* neW = (const float*)d_in[3];
    const float* neb = (const float*)d_in[4];
    const float* cW1 = (const float*)d_in[5];
    const float* cb1 = (const float*)d_in[6];
    const float* cW2 = (const float*)d_in[7];
    const float* cb2 = (const float*)d_in[8];
    const float* eW  = (const float*)d_in[9];
    const float* eb  = (const float*)d_in[10];
    const float* dW  = (const float*)d_in[11];
    const float* db  = (const float*)d_in[12];
    const float* tpW = (const float*)d_in[13];
    const float* tpb = (const float*)d_in[14];

    int N = in_sizes[0] / NDIM;
    int E = in_sizes[1] / 2;

    char* w = (char*)d_ws;
    auto alloc = [&](size_t bytes) {
        void* p = (void*)w;
        w += (bytes + 255) & ~(size_t)255;
        return p;
    };
    float*     temb   = (float*)alloc(64 * 4);
    _Float16*  hA     = (_Float16*)alloc((size_t)N * HID * 2);
    _Float16*  hB     = (_Float16*)alloc((size_t)N * HID * 2);
    _Float16*  Atab   = (_Float16*)alloc((size_t)N * HID * 2);
    _Float16*  Btab   = (_Float16*)alloc((size_t)N * HID * 2);
    _Float16*  WABT   = (_Float16*)alloc((size_t)NCONV * 2 * HID * HID * 2);
    _Float16*  W2T    = (_Float16*)alloc((size_t)NCONV * HID * HID * 2);
    _Float16*  encT   = (_Float16*)alloc((size_t)HID * HID * 2);
    int*       deg    = (int*)alloc((size_t)N * 4);
    int*       rowptr = (int*)alloc((size_t)(N + 1) * 4);
    int*       cursor = (int*)alloc((size_t)N * 4);
    int*       elist  = (int*)alloc((size_t)E * 4);

    // weights + time embedding + node embedding
    int prep_total = NCONV * HID * HID + HID * HID;
    prep_weights<<<(prep_total + 255) / 256, 256, 0, stream>>>(cW1, cW2, eW, WABT, W2T, encT);
    time_emb_kernel<<<1, 64, 0, stream>>>(t, tpW, tpb, temb);
    node_emb_kernel<<<N, HID, 0, stream>>>(x, temb, neW, neb, hA, N);

    // CSR by dst
    hipMemsetAsync(deg, 0, (size_t)N * 4, stream);
    count_deg<<<(E + 255) / 256, 256, 0, stream>>>(ei, deg, E);
    scan_csr<<<1, 1024, 0, stream>>>(deg, rowptr, cursor, N);
    fill_csr<<<(E + 255) / 256, 256, 0, stream>>>(ei, cursor, elist, E);

    int nmt = (N + 15) / 16;
    int ab_blocks = (nmt * 8 + 3) / 4;      // 8 j-pairs per m-tile
    int fc_blocks = (nmt * 4 + 3) / 4;      // OUT=128 -> JW=4
    int ec_blocks = 512;                    // 512 thr/block: 2 blocks/CU, 16 waves/CU

    _Float16* cur = hA;
    for (int l = 0; l < NCONV; l++) {
        if (l == 4) {
            gemm_h<128><<<fc_blocks, 256, 0, stream>>>(cur, encT, eb, hB, N);
            cur = hB;
        }
        ab_gemm<<<ab_blocks, 256, 0, stream>>>(cur, WABT + (size_t)l * 2 * HID * HID,
                                               cb1 + (size_t)l * HID, Atab, Btab, N);
        edge_conv<<<ec_blocks, 512, 0, stream>>>(Atab, Btab, W2T + (size_t)l * HID * HID,
                                                 cb2 + (size_t)l * HID, rowptr, elist, cur, N);
    }

    fc_dec<<<N, HID, 0, stream>>>(cur, dW, db, (float*)d_out, N);
}

// Round 10
// 305.458 us; speedup vs baseline: 1.3069x; 1.1013x over previous
//
#include <hip/hip_runtime.h>
#include <hip/hip_fp16.h>

typedef _Float16 half8 __attribute__((ext_vector_type(8)));
typedef float f32x4 __attribute__((ext_vector_type(4)));
typedef float f32x16 __attribute__((ext_vector_type(16)));

#define HID 128
#define NDIM 16
#define NCONV 8

static __device__ __forceinline__ half8 load_h8(const _Float16* p) {
    return *(const half8*)p;
}

// ---------------- weight prep: f16 transposed weights ----------------
// Index mapping: j = fast (r%HID) so GLOBAL LOADS are coalesced; the transposed
// stores are strided but fire-and-forget (absorbed by L2 write combining).
// WABT[l] rows j<128: W1A_T[j][k]=W1[k][j]-W1[128+k][j]; rows 128+j: W1B_T[j][k]=W1[128+k][j]
// W2T[l][j][k] = W2[k][j].  Tails: encT[j][k]=eW[k][j]; dWT[j][k]=dW[k*16+j] (j<16).
__global__ void prep_weights(const float* __restrict__ W1, const float* __restrict__ W2,
                             const float* __restrict__ eW, const float* __restrict__ dW,
                             _Float16* __restrict__ WABT, _Float16* __restrict__ W2T,
                             _Float16* __restrict__ encT, _Float16* __restrict__ dWT) {
    int idx = blockIdx.x * blockDim.x + threadIdx.x;
    int total = NCONV * HID * HID;
    if (idx < total) {
        int l = idx / (HID * HID);
        int r = idx % (HID * HID);
        int k = r / HID;        // slow: input row
        int j = r % HID;        // fast: input col -> coalesced loads
        const float* w1 = W1 + (size_t)l * 2 * HID * HID;
        float top = w1[k * HID + j];
        float bot = w1[(HID + k) * HID + j];
        _Float16* wab = WABT + (size_t)l * 2 * HID * HID;
        wab[j * HID + k] = (_Float16)(top - bot);
        wab[(HID + j) * HID + k] = (_Float16)bot;
        const float* w2 = W2 + (size_t)l * HID * HID;
        W2T[(size_t)l * HID * HID + j * HID + k] = (_Float16)w2[k * HID + j];
    } else if (idx < total + HID * HID) {
        int r = idx - total;
        int k = r / HID;
        int j = r % HID;
        encT[j * HID + k] = (_Float16)eW[k * HID + j];
    } else if (idx < total + HID * HID + 16 * HID) {
        int r = idx - total - HID * HID;
        int j = r / HID;        // 0..15
        int k = r % HID;
        dWT[j * HID + k] = (_Float16)dW[k * NDIM + j];
    }
}

// ---------------- node embedding (time emb fused): h = (x + temb) @ neW + neb -> f16 ----
__global__ __launch_bounds__(256) void node_emb_kernel(const float* __restrict__ x,
                                                       const float* __restrict__ t,
                                                       const float* __restrict__ tpW,
                                                       const float* __restrict__ tpb,
                                                       const float* __restrict__ W,
                                                       const float* __restrict__ b,
                                                       _Float16* __restrict__ h16, int n) {
    __shared__ float sc[64];
    __shared__ float temb[NDIM];
    int tid = threadIdx.x;
    float tv = t[0];
    if (tid < 32) {
        float f = expf(-4.0f + 8.0f * (float)tid / 31.0f);
        sc[tid] = sinf(tv * f);
        sc[32 + tid] = cosf(tv * f);
    }
    __syncthreads();
    if (tid < 16) {
        float acc = tpb[tid];
        for (int k = 0; k < 64; k++) acc += sc[k] * tpW[k * NDIM + tid];
        temb[tid] = acc;
    }
    __syncthreads();
    int j = tid & 127;
    int half = tid >> 7;
    for (int base = blockIdx.x * 2; base < n; base += gridDim.x * 2) {
        int node = base + half;
        if (node < n) {
            const float* xr = x + (size_t)node * NDIM;
            float acc = b[j];
            #pragma unroll
            for (int d = 0; d < NDIM; d++) acc += (xr[d] + temb[d]) * W[d * HID + j];
            h16[(size_t)node * HID + j] = (_Float16)acc;
        }
    }
}

// ---------------- CSR build ----------------
__global__ void count_deg(const int* __restrict__ ei, int* __restrict__ deg, int E) {
    int e = blockIdx.x * blockDim.x + threadIdx.x;
    if (e < E) atomicAdd(&deg[ei[E + e]], 1);   // dst row
}

__global__ void scan_csr(const int* __restrict__ deg, int* __restrict__ rowptr,
                         int* __restrict__ cursor, int n) {
    __shared__ int part[1024];
    int t = threadIdx.x;
    int chunk = (n + 1023) / 1024;
    int base = t * chunk;
    int s = 0;
    for (int i = 0; i < chunk; i++) {
        int id = base + i;
        if (id < n) s += deg[id];
    }
    part[t] = s;
    __syncthreads();
    for (int off = 1; off < 1024; off <<= 1) {
        int v = 0;
        if (t >= off) v = part[t - off];
        __syncthreads();
        part[t] += v;
        __syncthreads();
    }
    int pre = (t == 0) ? 0 : part[t - 1];
    for (int i = 0; i < chunk; i++) {
        int id = base + i;
        if (id < n) {
            rowptr[id] = pre;
            cursor[id] = pre;
            pre += deg[id];
        }
    }
    if (t == 1023) rowptr[n] = part[1023];
}

__global__ void fill_csr(const int* __restrict__ ei, int* __restrict__ cursor,
                         int* __restrict__ elist, int E) {
    int e = blockIdx.x * blockDim.x + threadIdx.x;
    if (e < E) {
        int d = ei[E + e];
        int pos = atomicAdd(&cursor[d], 1);
        elist[pos] = ei[e];   // src
    }
}

// ---------------- AB gemm: Atab[n][128] = h@W1A + b1 ; Btab[n][128] = h@W1B ----------------
// Split tables: the gathered table (Btab) is 2.5 MB -> L2-resident per XCD.
__global__ __launch_bounds__(256) void ab_gemm(const _Float16* __restrict__ A,
                                               const _Float16* __restrict__ WT,
                                               const float* __restrict__ bias,
                                               _Float16* __restrict__ Atab,
                                               _Float16* __restrict__ Btab, int n) {
    int gw = (blockIdx.x * blockDim.x + threadIdx.x) >> 6;
    int lane = threadIdx.x & 63;
    int nmt = (n + 15) >> 4;
    if (gw >= nmt * 8) return;
    int mt = gw >> 3;
    int jp = gw & 7;
    int c = lane & 15;
    int kq = lane >> 4;

    int arow = mt * 16 + c;
    half8 a[4];
    #pragma unroll
    for (int kb = 0; kb < 4; kb++) {
        if (arow < n) a[kb] = load_h8(A + (size_t)arow * HID + kb * 32 + kq * 8);
        else          a[kb] = (half8)(_Float16)0;
    }

    f32x4 acc[2];
    #pragma unroll
    for (int p = 0; p < 2; p++) {
        acc[p][0] = 0.f; acc[p][1] = 0.f; acc[p][2] = 0.f; acc[p][3] = 0.f;
        int wrow = (jp * 2 + p) * 16 + c;
        #pragma unroll
        for (int kb = 0; kb < 4; kb++) {
            half8 b = load_h8(WT + (size_t)wrow * HID + kb * 32 + kq * 8);
            acc[p] = __builtin_amdgcn_mfma_f32_16x16x32_f16(a[kb], b, acc[p], 0, 0, 0);
        }
    }

    #pragma unroll
    for (int p = 0; p < 2; p++) {
        int col = (jp * 2 + p) * 16 + c;
        float bv = (col < HID) ? bias[col] : 0.f;
        _Float16* dst = (col < HID) ? Atab : Btab;
        int dcol = col & (HID - 1);
        #pragma unroll
        for (int r = 0; r < 4; r++) {
            int row = mt * 16 + kq * 4 + r;
            if (row < n) dst[(size_t)row * HID + dcol] = (_Float16)(acc[p][r] + bv);
        }
    }
}

// ---------------- generic node GEMM: Y[n][OUT] = A[n][128] @ WT^T + bias ----------------
template<int OUT>
__global__ __launch_bounds__(256) void gemm_h(const _Float16* __restrict__ A,
                                              const _Float16* __restrict__ WT,
                                              const float* __restrict__ bias,
                                              _Float16* __restrict__ Y, int n) {
    constexpr int JW = OUT / 32;    // j-pairs per m-tile
    int gw = (blockIdx.x * blockDim.x + threadIdx.x) >> 6;
    int lane = threadIdx.x & 63;
    int nmt = (n + 15) >> 4;
    if (gw >= nmt * JW) return;
    int mt = gw / JW;
    int jp = gw % JW;
    int c = lane & 15;
    int kq = lane >> 4;

    int arow = mt * 16 + c;
    half8 a[4];
    #pragma unroll
    for (int kb = 0; kb < 4; kb++) {
        if (arow < n) a[kb] = load_h8(A + (size_t)arow * HID + kb * 32 + kq * 8);
        else          a[kb] = (half8)(_Float16)0;
    }

    f32x4 acc[2];
    #pragma unroll
    for (int p = 0; p < 2; p++) {
        acc[p][0] = 0.f; acc[p][1] = 0.f; acc[p][2] = 0.f; acc[p][3] = 0.f;
        int wrow = (jp * 2 + p) * 16 + c;
        #pragma unroll
        for (int kb = 0; kb < 4; kb++) {
            half8 b = load_h8(WT + (size_t)wrow * HID + kb * 32 + kq * 8);
            acc[p] = __builtin_amdgcn_mfma_f32_16x16x32_f16(a[kb], b, acc[p], 0, 0, 0);
        }
    }

    #pragma unroll
    for (int p = 0; p < 2; p++) {
        int col = (jp * 2 + p) * 16 + c;
        float bv = (col < HID) ? bias[col] : 0.f;
        #pragma unroll
        for (int r = 0; r < 4; r++) {
            int row = mt * 16 + kq * 4 + r;
            if (row < n) Y[(size_t)row * OUT + col] = (_Float16)(acc[p][r] + bv);
        }
    }
}

// ---------------- EdgeConv: out[v][j] = max_e relu(A[v]+B[src_e]) @ W2 + b2 ----------------
// 32x32x16 MFMA, 32-edge tiles (~1 tile/node). Register-liveness-capped variant:
//  - af is RELOADED per tile from L1 (wave-broadcast, ~free) instead of held live;
//  - the 4 cb blocks are explicitly unrolled with sched_barrier(0) between them so
//    only ONE f32x16 accumulator is live at a time.
// Target live set ~100-110 VGPR -> 16 waves/CU (was ~150 -> 8 waves/CU, which is why
// r6's LDS-traffic halving was occupancy-cancelled).
// W2 in LDS fragment-major (0 bank conflicts, r3-verified). Gathers hit L2-resident Btab.
// NOTE: no min-waves launch bound (r2/r3 lesson: forced budget -> 200 MB spills).
__global__ __launch_bounds__(512) void edge_conv(const _Float16* __restrict__ Atab,
                                                 const _Float16* __restrict__ Btab,
                                                 const _Float16* __restrict__ W2T_l,
                                                 const float* __restrict__ b2_l,
                                                 const int* __restrict__ rowptr,
                                                 const int* __restrict__ elist,
                                                 _Float16* __restrict__ hout, int n) {
    __shared__ _Float16 w2s[2048 * 8];   // 32 frags (kb*4+cb) x 64 lanes x 16B = 32 KB
    __shared__ float b2s[HID];
    int tid = threadIdx.x;
    #pragma unroll
    for (int i = 0; i < 4; i++) {
        int fid = i * 512 + tid;     // 0..2047
        int ln = fid & 63;
        int grp = fid >> 6;          // kb*4+cb
        int kb = grp >> 2;
        int cb = grp & 3;
        *(half8*)(w2s + (size_t)fid * 8) =
            load_h8(W2T_l + (size_t)(cb * 32 + (ln & 31)) * HID + kb * 16 + (ln >> 5) * 8);
    }
    if (tid < HID) b2s[tid] = b2_l[tid];
    __syncthreads();

    int lane = tid & 63;
    int er = lane & 31;     // edge-row within tile / output col within cb block
    int hi = lane >> 5;     // k-half
    int gw = (blockIdx.x * blockDim.x + tid) >> 6;
    int nw = (gridDim.x * blockDim.x) >> 6;
    if (gw >= n) return;

    // ---- pipeline prologue (scalar rowptr/src prefetch only — r8 lesson) ----
    int v = gw;
    int rbeg0 = rowptr[v];
    int deg0 = rowptr[v + 1] - rbeg0;
    int src0 = (er < deg0) ? elist[rbeg0 + er] : v;
    int v1 = v + nw;
    int rbeg1 = 0, deg1 = 0;
    if (v1 < n) { rbeg1 = rowptr[v1]; deg1 = rowptr[v1 + 1] - rbeg1; }

    while (true) {
        int vn = v + nw;
        int vn2 = vn + nw;
        int rbeg2 = 0, deg2 = 0;
        if (vn2 < n) { rbeg2 = rowptr[vn2]; deg2 = rowptr[vn2 + 1] - rbeg2; }
        int src1 = (er < deg1) ? elist[rbeg1 + er] : vn;

        int ntile = (deg0 + 32) >> 5;        // ceil((deg0+1)/32), pad = self-loop
        float macc0 = -3.0e38f, macc1 = -3.0e38f, macc2 = -3.0e38f, macc3 = -3.0e38f;

        int src = src0;
        for (int tI = 0; tI < ntile; tI++) {
            // per-tile af reload (L1 broadcast) + B gather; s = relu(af + b)
            const _Float16* ap = Atab + (size_t)v * HID + hi * 8;
            const _Float16* bp = Btab + (size_t)src * HID + hi * 8;
            half8 s[8];
            #pragma unroll
            for (int kb = 0; kb < 8; kb++) {
                half8 t2 = load_h8(ap + kb * 16) + load_h8(bp + kb * 16);
                #pragma unroll
                for (int e2 = 0; e2 < 8; e2++) t2[e2] = (t2[e2] > (_Float16)0) ? t2[e2] : (_Float16)0;
                s[kb] = t2;
            }

            // prefetch next tile's src (overlaps with compute)
            int en = (tI + 1) * 32 + er;
            int srcn = (tI + 1 < ntile && en < deg0) ? elist[rbeg0 + en] : v;

#define CB_BLOCK(CB, MREF)                                                              \
            {                                                                           \
                f32x16 d;                                                               \
                _Pragma("unroll")                                                       \
                for (int e2 = 0; e2 < 16; e2++) d[e2] = 0.f;                            \
                _Pragma("unroll")                                                       \
                for (int kb = 0; kb < 8; kb++) {                                        \
                    half8 w = *(const half8*)(w2s + ((size_t)((kb * 4 + CB) * 64 + lane)) * 8); \
                    d = __builtin_amdgcn_mfma_f32_32x32x16_f16(s[kb], w, d, 0, 0, 0);   \
                }                                                                       \
                float m0 = fmaxf(fmaxf(d[0], d[1]), fmaxf(d[2], d[3]));                 \
                float m1 = fmaxf(fmaxf(d[4], d[5]), fmaxf(d[6], d[7]));                 \
                float m2 = fmaxf(fmaxf(d[8], d[9]), fmaxf(d[10], d[11]));               \
                float m3 = fmaxf(fmaxf(d[12], d[13]), fmaxf(d[14], d[15]));             \
                MREF = fmaxf(MREF, fmaxf(fmaxf(m0, m1), fmaxf(m2, m3)));                \
            }

            CB_BLOCK(0, macc0)
            __builtin_amdgcn_sched_barrier(0);   // cap accumulator liveness to 1
            CB_BLOCK(1, macc1)
            __builtin_amdgcn_sched_barrier(0);
            CB_BLOCK(2, macc2)
            __builtin_amdgcn_sched_barrier(0);
            CB_BLOCK(3, macc3)
#undef CB_BLOCK
            src = srcn;
        }

        // merge k-half partners (other 16 rows) and write
#define WR(CB, MREF)                                                                    \
        {                                                                               \
            float m = fmaxf(MREF, __shfl_xor(MREF, 32));                                \
            m += b2s[CB * 32 + er];                                                     \
            if (lane < 32) hout[(size_t)v * HID + CB * 32 + er] = (_Float16)m;          \
        }
        WR(0, macc0) WR(1, macc1) WR(2, macc2) WR(3, macc3)
#undef WR

        // ---- rotate pipeline ----
        v = vn;
        if (v >= n) break;
        src0 = src1;
        rbeg0 = rbeg1; deg0 = deg1;
        rbeg1 = rbeg2; deg1 = deg2;
    }
}

// ---------------- decoder FC via MFMA: out[n][16] = h @ dWT^T + db (f32 out) ----------------
// One 16-row m-tile per wave, single 16-col tile (dWT is [16][128] f16).
__global__ __launch_bounds__(256) void fc_dec_mfma(const _Float16* __restrict__ h16,
                                                   const _Float16* __restrict__ dWT,
                                                   const float* __restrict__ db,
                                                   float* __restrict__ out, int n) {
    int gw = (blockIdx.x * blockDim.x + threadIdx.x) >> 6;
    int lane = threadIdx.x & 63;
    int nmt = (n + 15) >> 4;
    if (gw >= nmt) return;
    int c = lane & 15;
    int kq = lane >> 4;

    int arow = gw * 16 + c;
    f32x4 acc = {0.f, 0.f, 0.f, 0.f};
    #pragma unroll
    for (int kb = 0; kb < 4; kb++) {
        half8 a = (arow < n) ? load_h8(h16 + (size_t)arow * HID + kb * 32 + kq * 8)
                             : (half8)(_Float16)0;
        half8 b = load_h8(dWT + (size_t)c * HID + kb * 32 + kq * 8);
        acc = __builtin_amdgcn_mfma_f32_16x16x32_f16(a, b, acc, 0, 0, 0);
    }
    float bv = db[c];
    #pragma unroll
    for (int r = 0; r < 4; r++) {
        int row = gw * 16 + kq * 4 + r;
        if (row < n) out[(size_t)row * NDIM + c] = acc[r] + bv;
    }
}

// ---------------- host ----------------
extern "C" void kernel_launch(void* const* d_in, const int* in_sizes, int n_in,
                              void* d_out, int out_size, void* d_ws, size_t ws_size,
                              hipStream_t stream) {
    const float* x   = (const float*)d_in[0];
    const int*   ei  = (const int*)d_in[1];
    const float* t   = (const float*)d_in[2];
    const float* neW = (const float*)d_in[3];
    const float* neb = (const float*)d_in[4];
    const float* cW1 = (const float*)d_in[5];
    const float* cb1 = (const float*)d_in[6];
    const float* cW2 = (const float*)d_in[7];
    const float* cb2 = (const float*)d_in[8];
    const float* eW  = (const float*)d_in[9];
    const float* eb  = (const float*)d_in[10];
    const float* dW  = (const float*)d_in[11];
    const float* db  = (const float*)d_in[12];
    const float* tpW = (const float*)d_in[13];
    const float* tpb = (const float*)d_in[14];

    int N = in_sizes[0] / NDIM;
    int E = in_sizes[1] / 2;

    char* w = (char*)d_ws;
    auto alloc = [&](size_t bytes) {
        void* p = (void*)w;
        w += (bytes + 255) & ~(size_t)255;
        return p;
    };
    _Float16*  hA     = (_Float16*)alloc((size_t)N * HID * 2);
    _Float16*  hB     = (_Float16*)alloc((size_t)N * HID * 2);
    _Float16*  Atab   = (_Float16*)alloc((size_t)N * HID * 2);
    _Float16*  Btab   = (_Float16*)alloc((size_t)N * HID * 2);
    _Float16*  WABT   = (_Float16*)alloc((size_t)NCONV * 2 * HID * HID * 2);
    _Float16*  W2T    = (_Float16*)alloc((size_t)NCONV * HID * HID * 2);
    _Float16*  encT   = (_Float16*)alloc((size_t)HID * HID * 2);
    _Float16*  dWT    = (_Float16*)alloc((size_t)16 * HID * 2);
    int*       deg    = (int*)alloc((size_t)N * 4);
    int*       rowptr = (int*)alloc((size_t)(N + 1) * 4);
    int*       cursor = (int*)alloc((size_t)N * 4);
    int*       elist  = (int*)alloc((size_t)E * 4);

    // weights + node embedding (time emb fused)
    int prep_total = NCONV * HID * HID + HID * HID + 16 * HID;
    prep_weights<<<(prep_total + 255) / 256, 256, 0, stream>>>(cW1, cW2, eW, dW,
                                                               WABT, W2T, encT, dWT);
    node_emb_kernel<<<1024, 256, 0, stream>>>(x, t, tpW, tpb, neW, neb, hA, N);

    // CSR by dst
    hipMemsetAsync(deg, 0, (size_t)N * 4, stream);
    count_deg<<<(E + 255) / 256, 256, 0, stream>>>(ei, deg, E);
    scan_csr<<<1, 1024, 0, stream>>>(deg, rowptr, cursor, N);
    fill_csr<<<(E + 255) / 256, 256, 0, stream>>>(ei, cursor, elist, E);

    int nmt = (N + 15) / 16;
    int ab_blocks = (nmt * 8 + 3) / 4;      // 8 j-pairs per m-tile
    int fc_blocks = (nmt * 4 + 3) / 4;      // OUT=128 -> JW=4
    int ec_blocks = 512;                    // 512 thr/block: 2 blocks/CU, 16 waves/CU

    _Float16* cur = hA;
    for (int l = 0; l < NCONV; l++) {
        if (l == 4) {
            gemm_h<128><<<fc_blocks, 256, 0, stream>>>(cur, encT, eb, hB, N);
            cur = hB;
        }
        ab_gemm<<<ab_blocks, 256, 0, stream>>>(cur, WABT + (size_t)l * 2 * HID * HID,
                                               cb1 + (size_t)l * HID, Atab, Btab, N);
        edge_conv<<<ec_blocks, 512, 0, stream>>>(Atab, Btab, W2T + (size_t)l * HID * HID,
                                                 cb2 + (size_t)l * HID, rowptr, elist, cur, N);
    }

    fc_dec_mfma<<<(nmt + 3) / 4, 256, 0, stream>>>(cur, dWT, db, (float*)d_out, N);
}